// Round 4
// baseline (1577.886 us; speedup 1.0000x reference)
//
#include <hip/hip_runtime.h>
#include <stdint.h>

// ============================================================================
// JAX threefry2x32 PRNG reproduction (partitionable semantics, verified R0).
// ============================================================================
struct U2 { unsigned a, b; };

__device__ __forceinline__ unsigned rotl32(unsigned v, int r) {
  return (v << r) | (v >> (32 - r));
}

__device__ __forceinline__ U2 tf(U2 k, unsigned x0, unsigned x1) {
  unsigned ks0 = k.a, ks1 = k.b, ks2 = k.a ^ k.b ^ 0x1BD11BDAu;
  x0 += ks0; x1 += ks1;
#define TFG(RA, RB, RC, RD, KA, KB, INC)                  \
  x0 += x1; x1 = rotl32(x1, RA); x1 ^= x0;                \
  x0 += x1; x1 = rotl32(x1, RB); x1 ^= x0;                \
  x0 += x1; x1 = rotl32(x1, RC); x1 ^= x0;                \
  x0 += x1; x1 = rotl32(x1, RD); x1 ^= x0;                \
  x0 += KA; x1 += KB + INC;
  TFG(13, 15, 26, 6, ks1, ks2, 1u)
  TFG(17, 29, 16, 24, ks2, ks0, 2u)
  TFG(13, 15, 26, 6, ks0, ks1, 3u)
  TFG(17, 29, 16, 24, ks1, ks2, 4u)
  TFG(13, 15, 26, 6, ks2, ks0, 5u)
#undef TFG
  U2 r; r.a = x0; r.b = x1; return r;
}

__device__ __forceinline__ U2 split_key(U2 key, int num, int j) {
  (void)num;
  return tf(key, 0u, (unsigned)j);
}
__device__ __forceinline__ unsigned random_bits(U2 key, int n, unsigned e) {
  (void)n;
  U2 r = tf(key, 0u, e);
  return r.a ^ r.b;
}

__device__ __forceinline__ U2 root_key() { U2 k; k.a = 0u; k.b = 42u; return k; }

__device__ __forceinline__ float jax_uniform(U2 key, int n, unsigned e,
                                             float minv, float maxv) {
  unsigned b = random_bits(key, n, e);
  float u = __uint_as_float((b >> 9) | 0x3f800000u) - 1.0f;
  float r = u * (maxv - minv) + minv;
  return fmaxf(minv, r);
}

#define ROTR 0.7853981633974483f

__device__ __forceinline__ void compute_R(float vx, float vy, float vz,
                                          float R[3][3]) {
  float nsq = vx * vx + vy * vy + vz * vz;
  float theta = sqrtf(nsq);
  if (theta < 1e-8f) {
    R[0][0] = 1.f; R[0][1] = 0.f; R[0][2] = 0.f;
    R[1][0] = 0.f; R[1][1] = 1.f; R[1][2] = 0.f;
    R[2][0] = 0.f; R[2][1] = 0.f; R[2][2] = 1.f;
    return;
  }
  float m = fmaxf(theta, 1e-8f);
  float kx = vx / m, ky = vy / m, kz = vz / m;
  float s = sinf(theta), c = cosf(theta);
  float K[3][3] = {{0.f, -kz, ky}, {kz, 0.f, -kx}, {-ky, kx, 0.f}};
  float K2[3][3];
#pragma unroll
  for (int i = 0; i < 3; i++)
#pragma unroll
    for (int j = 0; j < 3; j++)
      K2[i][j] = fmaf(K[i][2], K[2][j], fmaf(K[i][1], K[1][j], K[i][0] * K[0][j]));
  float omc = 1.0f - c;
#pragma unroll
  for (int i = 0; i < 3; i++)
#pragma unroll
    for (int j = 0; j < 3; j++)
      R[i][j] = ((i == j) ? 1.0f : 0.0f) + s * K[i][j] + omc * K2[i][j];
}

// composite sort key for stream s (0:src r1, 1:src r2, 2:tgt r1, 3:tgt r2)
__device__ __forceinline__ unsigned long long make_composite(int s, int i) {
  U2 root = root_key();
  U2 kp = split_key(root, 5, s >> 1);
  U2 key;
  if ((s & 1) == 0) {
    key = split_key(kp, 2, 1);
  } else {
    U2 kA = split_key(kp, 2, 0);
    key = split_key(kA, 2, 1);
  }
  unsigned rb = random_bits(key, 16384, (unsigned)i);
  return ((unsigned long long)rb << 32) | (unsigned)i;
}

// ============================================================================
// Bucket-sort rank pipeline (verified R3).
// ============================================================================
__global__ __launch_bounds__(256) void hist_kernel(unsigned* __restrict__ hist) {
  int gid = blockIdx.x * 256 + threadIdx.x;  // 65536
  int s = gid >> 14, i = gid & 16383;
  unsigned long long c = make_composite(s, i);
  unsigned bucket = (unsigned)(c >> 56);
  atomicAdd(&hist[s * 256 + bucket], 1u);
}

__global__ __launch_bounds__(256) void prefix_kernel(
    const unsigned* __restrict__ hist, unsigned* __restrict__ base,
    unsigned* __restrict__ cursor) {
  __shared__ unsigned h[4][256];
  int t = threadIdx.x;
#pragma unroll
  for (int s = 0; s < 4; s++) h[s][t] = hist[s * 256 + t];
  __syncthreads();
#pragma unroll
  for (int s = 0; s < 4; s++) {
    unsigned acc = 0;
    for (int j = 0; j < 256; j++) acc += (j < t) ? h[s][j] : 0u;
    base[s * 256 + t] = acc;
    cursor[s * 256 + t] = acc;
  }
}

__global__ __launch_bounds__(256) void scatterb_kernel(
    unsigned* __restrict__ cursor, unsigned long long* __restrict__ sorted) {
  int gid = blockIdx.x * 256 + threadIdx.x;  // 65536
  int s = gid >> 14, i = gid & 16383;
  unsigned long long c = make_composite(s, i);
  unsigned bucket = (unsigned)(c >> 56);
  unsigned pos = atomicAdd(&cursor[s * 256 + bucket], 1u);
  sorted[(s << 14) + pos] = c;
}

__global__ __launch_bounds__(256) void rank_kernel(
    const unsigned long long* __restrict__ sorted,
    const unsigned* __restrict__ base, const unsigned* __restrict__ hist,
    unsigned* __restrict__ rank_all) {
  int gid = blockIdx.x * 256 + threadIdx.x;  // 65536
  int s = gid >> 14, k = gid & 16383;
  unsigned long long c = sorted[(s << 14) + k];
  unsigned bucket = (unsigned)(c >> 56);
  unsigned b0 = base[s * 256 + bucket];
  unsigned cnt = hist[s * 256 + bucket];
  unsigned less = 0;
  for (unsigned j = 0; j < cnt; j++)
    less += (sorted[(s << 14) + b0 + j] < c) ? 1u : 0u;
  unsigned i = (unsigned)(c & 0xffffffffull);
  rank_all[(s << 14) + i] = b0 + less;
}

// x1[perm][rank1[i]] = i   (streams 0,2)
__global__ __launch_bounds__(256) void scatter_kernel(
    const unsigned* __restrict__ rank_all, unsigned* __restrict__ x1buf) {
  int gid = blockIdx.x * 256 + threadIdx.x;  // 32768
  int perm = gid >> 14, i = gid & 16383;
  unsigned r = rank_all[((perm * 2) << 14) + i];
  x1buf[(perm << 14) + (int)r] = (unsigned)i;
}

// idx[perm][rank2[i]] = x1[perm][i] for rank2[i] < 128  (streams 1,3)
__global__ __launch_bounds__(256) void idx_kernel(
    const unsigned* __restrict__ rank_all, const unsigned* __restrict__ x1buf,
    int* __restrict__ idx) {
  int gid = blockIdx.x * 256 + threadIdx.x;  // 32768
  int perm = gid >> 14, i = gid & 16383;
  unsigned r = rank_all[((perm * 2 + 1) << 14) + i];
  if (r < 128u) idx[perm * 128 + (int)r] = (int)x1buf[(perm << 14) + i];
}

// ============================================================================
// setup: gather subsets + precompute yn (pop0 moved into de_persist).
// ============================================================================
__global__ __launch_bounds__(128) void setup_kernel(
    const float* __restrict__ source, const float* __restrict__ target,
    const int* __restrict__ idx, float* __restrict__ src,
    float* __restrict__ tgt, float* __restrict__ yn) {
  int b = blockIdx.x, tid = threadIdx.x;
  int is = idx[tid], it = idx[128 + tid];
#pragma unroll
  for (int d = 0; d < 3; d++)
    src[(b * 128 + tid) * 3 + d] = source[((size_t)b * 16384 + is) * 3 + d];
  float y0 = target[((size_t)b * 16384 + it) * 3 + 0];
  float y1 = target[((size_t)b * 16384 + it) * 3 + 1];
  float y2 = target[((size_t)b * 16384 + it) * 3 + 2];
  tgt[(b * 128 + tid) * 3 + 0] = y0;
  tgt[(b * 128 + tid) * 3 + 1] = y1;
  tgt[(b * 128 + tid) * 3 + 2] = y2;
  yn[b * 128 + tid] = y0 * y0 + y1 * y1 + y2 * y2;
}

// ============================================================================
// Chamfer eval core (bitwise-identical d2 / min sets / sum trees vs R3).
// colpart uses +rg rotation swizzle (address-only change, conflict-free).
// Valid return on tid 0.
// ============================================================================
__device__ __forceinline__ float eval_pose(
    float p0, float p1, float p2, float p3, float p4, float p5,
    float s0, float s1, float s2, int tid,
    const float4* syv, float4* xsv, float* colpart, float* rowpart) {
  float Rm[3][3];
  compute_R(p0, p1, p2, Rm);
  float x0 = fmaf(Rm[0][2], s2, fmaf(Rm[0][1], s1, Rm[0][0] * s0)) + p3;
  float x1 = fmaf(Rm[1][2], s2, fmaf(Rm[1][1], s1, Rm[1][0] * s0)) + p4;
  float x2 = fmaf(Rm[2][2], s2, fmaf(Rm[2][1], s1, Rm[2][0] * s0)) + p5;
  float xn = x0 * x0 + x1 * x1 + x2 * x2;
  xsv[tid] = make_float4(x0, x1, x2, xn);
  __syncthreads();
  int rg = tid & 31, cq = tid >> 5;
  float4 xr0 = xsv[4 * rg + 0];
  float4 xr1 = xsv[4 * rg + 1];
  float4 xr2 = xsv[4 * rg + 2];
  float4 xr3 = xsv[4 * rg + 3];
  float racc0 = 3.402823466e38f, racc1 = 3.402823466e38f;
  float racc2 = 3.402823466e38f, racc3 = 3.402823466e38f;
  float cacc[32];
#pragma unroll
  for (int cj = 0; cj < 32; cj++) {
    float4 y = syv[(cq << 5) + cj];
    float cr0 = fmaf(xr0.z, y.z, fmaf(xr0.y, y.y, xr0.x * y.x));
    float d0 = (xr0.w + y.w) - 2.0f * cr0; d0 = fmaxf(d0, 0.0f);
    float cr1 = fmaf(xr1.z, y.z, fmaf(xr1.y, y.y, xr1.x * y.x));
    float d1 = (xr1.w + y.w) - 2.0f * cr1; d1 = fmaxf(d1, 0.0f);
    float cr2 = fmaf(xr2.z, y.z, fmaf(xr2.y, y.y, xr2.x * y.x));
    float d2_ = (xr2.w + y.w) - 2.0f * cr2; d2_ = fmaxf(d2_, 0.0f);
    float cr3 = fmaf(xr3.z, y.z, fmaf(xr3.y, y.y, xr3.x * y.x));
    float d3 = (xr3.w + y.w) - 2.0f * cr3; d3 = fmaxf(d3, 0.0f);
    racc0 = fminf(racc0, d0); racc1 = fminf(racc1, d1);
    racc2 = fminf(racc2, d2_); racc3 = fminf(racc3, d3);
    cacc[cj] = fminf(fminf(d0, d1), fminf(d2_, d3));
  }
  rowpart[cq * 128 + 4 * rg + 0] = racc0;
  rowpart[cq * 128 + 4 * rg + 1] = racc1;
  rowpart[cq * 128 + 4 * rg + 2] = racc2;
  rowpart[cq * 128 + 4 * rg + 3] = racc3;
#pragma unroll
  for (int cj = 0; cj < 32; cj++)
    colpart[rg * 128 + (((cq << 5) + cj + rg) & 127)] = cacc[cj];
  __syncthreads();
  float rv = rowpart[tid];
  rv = fminf(rv, rowpart[128 + tid]);
  rv = fminf(rv, rowpart[256 + tid]);
  rv = fminf(rv, rowpart[384 + tid]);
  rowpart[tid] = rv;
  __syncthreads();
  for (int s = 64; s > 0; s >>= 1) {
    if (tid < s) rowpart[tid] += rowpart[tid + s];
    __syncthreads();
  }
  float rowsum = rowpart[0];
  __syncthreads();
  float cv = colpart[tid & 127];
#pragma unroll 4
  for (int rg2 = 1; rg2 < 32; rg2++)
    cv = fminf(cv, colpart[rg2 * 128 + ((tid + rg2) & 127)]);
  rowpart[tid] = cv;
  __syncthreads();
  for (int s = 64; s > 0; s >>= 1) {
    if (tid < s) rowpart[tid] += rowpart[tid + s];
    __syncthreads();
  }
  float colsum = rowpart[0];
  __syncthreads();
  return rowsum * 0.0078125f + colsum * 0.0078125f;
}

__device__ __forceinline__ float eff_pop(const float* pop_prev,
                                         const float* fit_prev,
                                         const float* trial_prev,
                                         const float* tfit_prev,
                                         int bq, int d) {
  return (tfit_prev[bq] < fit_prev[bq]) ? trial_prev[bq * 6 + d]
                                        : pop_prev[bq * 6 + d];
}

// ============================================================================
// Persistent DE kernel: 800 blocks x 128 threads, block = 2 particles of one
// batch. Init eval + 30 iterations + final selection, batch-local barriers.
// LDS ~22.6KB, launch_bounds(128,2) => >=4 blocks/CU => 1024 >= 800 resident.
// ============================================================================
__global__ __launch_bounds__(128, 2) void de_persist(
    const float* __restrict__ srcb, const float* __restrict__ tgtb,
    const float* __restrict__ ynb,
    float* __restrict__ popA, float* __restrict__ fitA,
    float* __restrict__ trialA, float* __restrict__ tfitA,
    float* __restrict__ popB, float* __restrict__ fitB,
    float* __restrict__ trialB, float* __restrict__ tfitB,
    unsigned* __restrict__ cnt, float* __restrict__ out) {
  int blk = blockIdx.x;           // 800
  int b = blk / 25, pu = blk % 25;
  int tid = threadIdx.x;
  int p0g = 2 * pu, p1g = 2 * pu + 1;
  int bp0 = b * 50 + p0g, bp1 = bp0 + 1;

  __shared__ float4 syv[128];
  __shared__ float4 xsv[128];
  __shared__ float colpart[32 * 128];
  __shared__ float rowpart[512];
  __shared__ float strial[2][6];
  __shared__ int sel[2][3];
  unsigned* lbits = (unsigned*)colpart;  // phase overlay (sync-separated)

  // persistent staging: src row in registers, target+yn in LDS (once)
  float s0 = srcb[(b * 128 + tid) * 3 + 0];
  float s1 = srcb[(b * 128 + tid) * 3 + 1];
  float s2 = srcb[(b * 128 + tid) * 3 + 2];
  {
    float y0 = tgtb[(b * 128 + tid) * 3 + 0];
    float y1 = tgtb[(b * 128 + tid) * 3 + 1];
    float y2 = tgtb[(b * 128 + tid) * 3 + 2];
    syv[tid] = make_float4(y0, y1, y2, ynb[b * 128 + tid]);
  }

  U2 root = root_key();

  // ---- epoch 0: pop0 + initial fitness ----
  {
    U2 k2 = split_key(root, 5, 2);
    U2 k3 = split_key(root, 5, 3);
    int u = tid >> 6, lt = tid & 63;
    if (lt < 6) {
      int p = 2 * pu + u, d = lt, bp = b * 50 + p;
      float val;
      if (p == 0) {
        val = 0.0f;
      } else {
        unsigned ridx = (unsigned)((b * 50 + p) * 3 + (d % 3));
        val = (d < 3) ? jax_uniform(k2, 4800, ridx, -ROTR, ROTR)
                      : jax_uniform(k3, 4800, ridx, -1.0f, 1.0f);
      }
      strial[u][d] = val;
      popA[bp * 6 + d] = val;
      trialA[bp * 6 + d] = val;
    }
  }
  __syncthreads();
  {
    float f0 = eval_pose(strial[0][0], strial[0][1], strial[0][2],
                         strial[0][3], strial[0][4], strial[0][5],
                         s0, s1, s2, tid, syv, xsv, colpart, rowpart);
    if (tid == 0) { fitA[bp0] = f0; tfitA[bp0] = f0; }
    float f1 = eval_pose(strial[1][0], strial[1][1], strial[1][2],
                         strial[1][3], strial[1][4], strial[1][5],
                         s0, s1, s2, tid, syv, xsv, colpart, rowpart);
    if (tid == 0) { fitA[bp1] = f1; tfitA[bp1] = f1; }
  }
  // barrier epoch 0
  __syncthreads();
  if (tid == 0) {
    __threadfence();
    atomicAdd(&cnt[b * 32 + 0], 1u);
    int fuel = 1 << 27;
    while (atomicAdd(&cnt[b * 32 + 0], 0u) < 25u && --fuel)
      __builtin_amdgcn_s_sleep(2);
  }
  __syncthreads();
  __threadfence();

  // ---- 30 DE iterations ----
  for (int it = 0; it < 30; it++) {
    const float* pop_prev   = (it & 1) ? popB : popA;
    const float* fit_prev   = (it & 1) ? fitB : fitA;
    const float* trial_prev = (it & 1) ? trialB : trialA;
    const float* tfit_prev  = (it & 1) ? tfitB : tfitA;
    float* pop_cur   = (it & 1) ? popA : popB;
    float* fit_cur   = (it & 1) ? fitA : fitB;
    float* trial_cur = (it & 1) ? trialA : trialB;
    float* tfit_cur  = (it & 1) ? tfitA : tfitB;

    U2 kloop = split_key(root, 5, 4);
    U2 kit = split_key(kloop, 30, it);
    U2 ka = split_key(kit, 3, 0);
    U2 kb = split_key(kit, 3, 1);
    U2 kc = split_key(kit, 3, 2);

    for (int e = tid; e < 150; e += 128) {
      int r = e / 50, q = e % 50;
      U2 pk = split_key(ka, 96, r * 32 + b);
      U2 sub = split_key(pk, 2, 1);
      lbits[r * 64 + q] = random_bits(sub, 50, (unsigned)q);
    }
    __syncthreads();
    for (int e = tid; e < 150; e += 128) {
      int r = e / 50, q = e % 50;
      unsigned bq = lbits[r * 64 + q];
      int cntq = 0;
      for (int j = 0; j < 50; j++) {
        unsigned bj = lbits[r * 64 + j];
        cntq += (bj < bq || (bj == bq && j < q)) ? 1 : 0;
      }
      if (cntq == p0g) sel[0][r] = q;
      if (cntq == p1g) sel[1][r] = q;
    }
    __syncthreads();
    {
      int u = tid >> 6, lt = tid & 63;
      int p = 2 * pu + u, bp = b * 50 + p;
      if (lt < 6) {
        int d = lt;
        int i1 = sel[u][0], i2 = sel[u][1], i3 = sel[u][2];
        float x1v = eff_pop(pop_prev, fit_prev, trial_prev, tfit_prev,
                            b * 50 + i1, d);
        float x2v = eff_pop(pop_prev, fit_prev, trial_prev, tfit_prev,
                            b * 50 + i2, d);
        float x3v = eff_pop(pop_prev, fit_prev, trial_prev, tfit_prev,
                            b * 50 + i3, d);
        float mu = x1v + 0.8f * (x2v - x3v);
        if (d < 3) mu = fminf(fmaxf(mu, -ROTR), ROTR);
        else       mu = fminf(fmaxf(mu, -1.0f), 1.0f);
        U2 kc1 = split_key(kc, 2, 0), kc2 = split_key(kc, 2, 1);
        unsigned hb = random_bits(kc1, 1600, (unsigned)bp);
        unsigned lb = random_bits(kc2, 1600, (unsigned)bp);
        int jr = (int)((((hb % 6u) * 4u) + (lb % 6u)) % 6u);
        unsigned rb = random_bits(kb, 9600, (unsigned)(bp * 6 + d));
        float uu = __uint_as_float((rb >> 9) | 0x3f800000u) - 1.0f;
        float pv = eff_pop(pop_prev, fit_prev, trial_prev, tfit_prev, bp, d);
        float tv = ((uu < 0.9f) || (d == jr)) ? mu : pv;
        strial[u][d] = tv;
        trial_cur[bp * 6 + d] = tv;
        pop_cur[bp * 6 + d] = pv;
      } else if (lt == 6) {
        float f = fit_prev[bp], tfv = tfit_prev[bp];
        fit_cur[bp] = (tfv < f) ? tfv : f;
      }
    }
    __syncthreads();
    float tf0 = eval_pose(strial[0][0], strial[0][1], strial[0][2],
                          strial[0][3], strial[0][4], strial[0][5],
                          s0, s1, s2, tid, syv, xsv, colpart, rowpart);
    if (tid == 0) tfit_cur[bp0] = tf0;
    float tf1 = eval_pose(strial[1][0], strial[1][1], strial[1][2],
                          strial[1][3], strial[1][4], strial[1][5],
                          s0, s1, s2, tid, syv, xsv, colpart, rowpart);
    if (tid == 0) tfit_cur[bp1] = tf1;
    // barrier epoch it+1
    __syncthreads();
    if (tid == 0) {
      __threadfence();
      atomicAdd(&cnt[b * 32 + it + 1], 1u);
      int fuel = 1 << 27;
      while (atomicAdd(&cnt[b * 32 + it + 1], 0u) < 25u && --fuel)
        __builtin_amdgcn_s_sleep(2);
    }
    __syncthreads();
    __threadfence();
  }

  // ---- final: epoch 30 state is in A buffers (30 & 1 == 0) ----
  if (pu == 0) {
    float* fl = rowpart;
    if (tid < 50) {
      int bp = b * 50 + tid;
      float f = fitA[bp], tfv = tfitA[bp];
      fl[tid] = (tfv < f) ? tfv : f;
    }
    __syncthreads();
    if (tid == 0) {
      int best = 0;
      for (int q = 1; q < 50; q++)
        if (fl[q] < fl[best]) best = q;
      int bp = b * 50 + best;
      bool useT = tfitA[bp] < fitA[bp];
      const float* v = useT ? (trialA + bp * 6) : (popA + bp * 6);
      float R[3][3];
      compute_R(v[0], v[1], v[2], R);
#pragma unroll
      for (int i = 0; i < 3; i++)
#pragma unroll
        for (int j = 0; j < 3; j++) out[b * 9 + i * 3 + j] = R[i][j];
      out[288 + b * 3 + 0] = v[3];
      out[288 + b * 3 + 1] = v[4];
      out[288 + b * 3 + 2] = v[5];
    }
  }
}

// aligned = source @ R_best^T + t_best  -> out[384:)
__global__ __launch_bounds__(256) void aligned_kernel(
    const float* __restrict__ source, float* __restrict__ out) {
  int gid = blockIdx.x * 256 + threadIdx.x;  // 524288
  int b = gid >> 14;
  const float* R = out + b * 9;
  const float* t = out + 288 + b * 3;
  float s0 = source[(size_t)gid * 3 + 0];
  float s1 = source[(size_t)gid * 3 + 1];
  float s2 = source[(size_t)gid * 3 + 2];
  float a0 = fmaf(R[2], s2, fmaf(R[1], s1, R[0] * s0)) + t[0];
  float a1 = fmaf(R[5], s2, fmaf(R[4], s1, R[3] * s0)) + t[1];
  float a2 = fmaf(R[8], s2, fmaf(R[7], s1, R[6] * s0)) + t[2];
  out[384 + (size_t)gid * 3 + 0] = a0;
  out[384 + (size_t)gid * 3 + 1] = a1;
  out[384 + (size_t)gid * 3 + 2] = a2;
}

// ============================================================================
extern "C" void kernel_launch(void* const* d_in, const int* in_sizes, int n_in,
                              void* d_out, int out_size, void* d_ws,
                              size_t ws_size, hipStream_t stream) {
  const float* source = (const float*)d_in[0];
  const float* target = (const float*)d_in[1];
  float* out = (float*)d_out;
  char* ws = (char*)d_ws;

  // --- workspace layout, fully disjoint (no overlays), ~1.2 MB ---
  unsigned long long* sorted = (unsigned long long*)(ws + 0);   // 524288
  unsigned* rank_all = (unsigned*)(ws + 524288);                // 262144
  unsigned* x1buf    = (unsigned*)(ws + 786432);                // 131072
  int* idx           = (int*)(ws + 917504);                     // 1024
  unsigned* hist     = (unsigned*)(ws + 918528);                // 4096
  unsigned* cnt      = (unsigned*)(ws + 922624);                // 4096 (adj.)
  unsigned* basep    = (unsigned*)(ws + 926720);                // 4096
  unsigned* cursor   = (unsigned*)(ws + 930816);                // 4096
  float* srcb        = (float*)(ws + 934912);                   // 49152
  float* tgtb        = (float*)(ws + 984064);                   // 49152
  float* ynb         = (float*)(ws + 1033216);                  // 16384
  float* popA        = (float*)(ws + 1049600);                  // 38400
  float* fitA        = (float*)(ws + 1088000);                  // 6400
  float* trialA      = (float*)(ws + 1094400);                  // 38400
  float* tfitA       = (float*)(ws + 1132800);                  // 6400
  float* popB        = (float*)(ws + 1139200);                  // 38400
  float* fitB        = (float*)(ws + 1177600);                  // 6400
  float* trialB      = (float*)(ws + 1184000);                  // 38400
  float* tfitB       = (float*)(ws + 1222400);                  // 6400

  hipMemsetAsync(ws + 918528, 0, 8192, stream);  // hist + cnt
  hist_kernel<<<256, 256, 0, stream>>>(hist);
  prefix_kernel<<<1, 256, 0, stream>>>(hist, basep, cursor);
  scatterb_kernel<<<256, 256, 0, stream>>>(cursor, sorted);
  rank_kernel<<<256, 256, 0, stream>>>(sorted, basep, hist, rank_all);
  scatter_kernel<<<128, 256, 0, stream>>>(rank_all, x1buf);
  idx_kernel<<<128, 256, 0, stream>>>(rank_all, x1buf, idx);
  setup_kernel<<<32, 128, 0, stream>>>(source, target, idx, srcb, tgtb, ynb);
  de_persist<<<800, 128, 0, stream>>>(srcb, tgtb, ynb,
                                      popA, fitA, trialA, tfitA,
                                      popB, fitB, trialB, tfitB, cnt, out);
  aligned_kernel<<<2048, 256, 0, stream>>>(source, out);
}

// Round 5
// 688.971 us; speedup vs baseline: 2.2902x; 2.2902x over previous
//
#include <hip/hip_runtime.h>
#include <stdint.h>

// ============================================================================
// JAX threefry2x32 PRNG reproduction (partitionable semantics, verified R0).
// ============================================================================
struct U2 { unsigned a, b; };

__device__ __forceinline__ unsigned rotl32(unsigned v, int r) {
  return (v << r) | (v >> (32 - r));
}

__device__ __forceinline__ U2 tf(U2 k, unsigned x0, unsigned x1) {
  unsigned ks0 = k.a, ks1 = k.b, ks2 = k.a ^ k.b ^ 0x1BD11BDAu;
  x0 += ks0; x1 += ks1;
#define TFG(RA, RB, RC, RD, KA, KB, INC)                  \
  x0 += x1; x1 = rotl32(x1, RA); x1 ^= x0;                \
  x0 += x1; x1 = rotl32(x1, RB); x1 ^= x0;                \
  x0 += x1; x1 = rotl32(x1, RC); x1 ^= x0;                \
  x0 += x1; x1 = rotl32(x1, RD); x1 ^= x0;                \
  x0 += KA; x1 += KB + INC;
  TFG(13, 15, 26, 6, ks1, ks2, 1u)
  TFG(17, 29, 16, 24, ks2, ks0, 2u)
  TFG(13, 15, 26, 6, ks0, ks1, 3u)
  TFG(17, 29, 16, 24, ks1, ks2, 4u)
  TFG(13, 15, 26, 6, ks2, ks0, 5u)
#undef TFG
  U2 r; r.a = x0; r.b = x1; return r;
}

__device__ __forceinline__ U2 split_key(U2 key, int num, int j) {
  (void)num;
  return tf(key, 0u, (unsigned)j);
}
__device__ __forceinline__ unsigned random_bits(U2 key, int n, unsigned e) {
  (void)n;
  U2 r = tf(key, 0u, e);
  return r.a ^ r.b;
}

__device__ __forceinline__ U2 root_key() { U2 k; k.a = 0u; k.b = 42u; return k; }

__device__ __forceinline__ float jax_uniform(U2 key, int n, unsigned e,
                                             float minv, float maxv) {
  unsigned b = random_bits(key, n, e);
  float u = __uint_as_float((b >> 9) | 0x3f800000u) - 1.0f;
  float r = u * (maxv - minv) + minv;
  return fmaxf(minv, r);
}

#define ROTR 0.7853981633974483f

__device__ __forceinline__ void compute_R(float vx, float vy, float vz,
                                          float R[3][3]) {
  float nsq = vx * vx + vy * vy + vz * vz;
  float theta = sqrtf(nsq);
  if (theta < 1e-8f) {
    R[0][0] = 1.f; R[0][1] = 0.f; R[0][2] = 0.f;
    R[1][0] = 0.f; R[1][1] = 1.f; R[1][2] = 0.f;
    R[2][0] = 0.f; R[2][1] = 0.f; R[2][2] = 1.f;
    return;
  }
  float m = fmaxf(theta, 1e-8f);
  float kx = vx / m, ky = vy / m, kz = vz / m;
  float s = sinf(theta), c = cosf(theta);
  float K[3][3] = {{0.f, -kz, ky}, {kz, 0.f, -kx}, {-ky, kx, 0.f}};
  float K2[3][3];
#pragma unroll
  for (int i = 0; i < 3; i++)
#pragma unroll
    for (int j = 0; j < 3; j++)
      K2[i][j] = fmaf(K[i][2], K[2][j], fmaf(K[i][1], K[1][j], K[i][0] * K[0][j]));
  float omc = 1.0f - c;
#pragma unroll
  for (int i = 0; i < 3; i++)
#pragma unroll
    for (int j = 0; j < 3; j++)
      R[i][j] = ((i == j) ? 1.0f : 0.0f) + s * K[i][j] + omc * K2[i][j];
}

// composite sort key for stream s (0:src r1, 1:src r2, 2:tgt r1, 3:tgt r2)
__device__ __forceinline__ unsigned long long make_composite(int s, int i) {
  U2 root = root_key();
  U2 kp = split_key(root, 5, s >> 1);
  U2 key;
  if ((s & 1) == 0) {
    key = split_key(kp, 2, 1);
  } else {
    U2 kA = split_key(kp, 2, 0);
    key = split_key(kA, 2, 1);
  }
  unsigned rb = random_bits(key, 16384, (unsigned)i);
  return ((unsigned long long)rb << 32) | (unsigned)i;
}

// ============================================================================
// Bucket-sort rank pipeline (verified R3).
// ============================================================================
__global__ __launch_bounds__(256) void hist_kernel(unsigned* __restrict__ hist) {
  int gid = blockIdx.x * 256 + threadIdx.x;  // 65536
  int s = gid >> 14, i = gid & 16383;
  unsigned long long c = make_composite(s, i);
  unsigned bucket = (unsigned)(c >> 56);
  atomicAdd(&hist[s * 256 + bucket], 1u);
}

__global__ __launch_bounds__(256) void prefix_kernel(
    const unsigned* __restrict__ hist, unsigned* __restrict__ base,
    unsigned* __restrict__ cursor) {
  __shared__ unsigned h[4][256];
  int t = threadIdx.x;
#pragma unroll
  for (int s = 0; s < 4; s++) h[s][t] = hist[s * 256 + t];
  __syncthreads();
#pragma unroll
  for (int s = 0; s < 4; s++) {
    unsigned acc = 0;
    for (int j = 0; j < 256; j++) acc += (j < t) ? h[s][j] : 0u;
    base[s * 256 + t] = acc;
    cursor[s * 256 + t] = acc;
  }
}

__global__ __launch_bounds__(256) void scatterb_kernel(
    unsigned* __restrict__ cursor, unsigned long long* __restrict__ sorted) {
  int gid = blockIdx.x * 256 + threadIdx.x;  // 65536
  int s = gid >> 14, i = gid & 16383;
  unsigned long long c = make_composite(s, i);
  unsigned bucket = (unsigned)(c >> 56);
  unsigned pos = atomicAdd(&cursor[s * 256 + bucket], 1u);
  sorted[(s << 14) + pos] = c;
}

__global__ __launch_bounds__(256) void rank_kernel(
    const unsigned long long* __restrict__ sorted,
    const unsigned* __restrict__ base, const unsigned* __restrict__ hist,
    unsigned* __restrict__ rank_all) {
  int gid = blockIdx.x * 256 + threadIdx.x;  // 65536
  int s = gid >> 14, k = gid & 16383;
  unsigned long long c = sorted[(s << 14) + k];
  unsigned bucket = (unsigned)(c >> 56);
  unsigned b0 = base[s * 256 + bucket];
  unsigned cnt = hist[s * 256 + bucket];
  unsigned less = 0;
  for (unsigned j = 0; j < cnt; j++)
    less += (sorted[(s << 14) + b0 + j] < c) ? 1u : 0u;
  unsigned i = (unsigned)(c & 0xffffffffull);
  rank_all[(s << 14) + i] = b0 + less;
}

// x1[perm][rank1[i]] = i   (streams 0,2)
__global__ __launch_bounds__(256) void scatter_kernel(
    const unsigned* __restrict__ rank_all, unsigned* __restrict__ x1buf) {
  int gid = blockIdx.x * 256 + threadIdx.x;  // 32768
  int perm = gid >> 14, i = gid & 16383;
  unsigned r = rank_all[((perm * 2) << 14) + i];
  x1buf[(perm << 14) + (int)r] = (unsigned)i;
}

// idx[perm][rank2[i]] = x1[perm][i] for rank2[i] < 128  (streams 1,3)
__global__ __launch_bounds__(256) void idx_kernel(
    const unsigned* __restrict__ rank_all, const unsigned* __restrict__ x1buf,
    int* __restrict__ idx) {
  int gid = blockIdx.x * 256 + threadIdx.x;  // 32768
  int perm = gid >> 14, i = gid & 16383;
  unsigned r = rank_all[((perm * 2 + 1) << 14) + i];
  if (r < 128u) idx[perm * 128 + (int)r] = (int)x1buf[(perm << 14) + i];
}

// ============================================================================
// setup: gather subsets, precompute yn, init population.
// ============================================================================
__global__ __launch_bounds__(128) void setup_kernel(
    const float* __restrict__ source, const float* __restrict__ target,
    const int* __restrict__ idx, float* __restrict__ src,
    float* __restrict__ tgt, float* __restrict__ yn, float* __restrict__ pop) {
  int b = blockIdx.x, tid = threadIdx.x;
  int is = idx[tid], it = idx[128 + tid];
#pragma unroll
  for (int d = 0; d < 3; d++)
    src[(b * 128 + tid) * 3 + d] = source[((size_t)b * 16384 + is) * 3 + d];
  float y0 = target[((size_t)b * 16384 + it) * 3 + 0];
  float y1 = target[((size_t)b * 16384 + it) * 3 + 1];
  float y2 = target[((size_t)b * 16384 + it) * 3 + 2];
  tgt[(b * 128 + tid) * 3 + 0] = y0;
  tgt[(b * 128 + tid) * 3 + 1] = y1;
  tgt[(b * 128 + tid) * 3 + 2] = y2;
  yn[b * 128 + tid] = y0 * y0 + y1 * y1 + y2 * y2;

  U2 root = root_key();
  U2 k2 = split_key(root, 5, 2);
  U2 k3 = split_key(root, 5, 3);
  for (int e = tid; e < 300; e += 128) {
    int p = e / 6, d = e % 6;
    float val;
    if (p == 0) {
      val = 0.0f;
    } else {
      unsigned ridx = (unsigned)((b * 50 + p) * 3 + (d % 3));
      if (d < 3) val = jax_uniform(k2, 4800, ridx, -ROTR, ROTR);
      else       val = jax_uniform(k3, 4800, ridx, -1.0f, 1.0f);
    }
    pop[(b * 50 + p) * 6 + d] = val;
  }
}

// ============================================================================
// Register-tiled chamfer eval core, LOW-LDS variant.
// Same d2 / min-sets / sum trees as R3 (bitwise identical results).
// Col-partial matrix (32x128) is time-multiplexed through an 8x132 buffer in
// 4 phases => total LDS ~11KB => one occupancy wave for 1600 blocks.
// ============================================================================
#define EVAL_CORE_BODY(POSE0, POSE1, POSE2, POSE3, POSE4, POSE5, OUTSTMT)      \
  {                                                                            \
    float Rm[3][3];                                                            \
    compute_R(POSE0, POSE1, POSE2, Rm);                                        \
    float t0 = POSE3, t1 = POSE4, t2 = POSE5;                                  \
    float x0 = fmaf(Rm[0][2], s2, fmaf(Rm[0][1], s1, Rm[0][0] * s0)) + t0;     \
    float x1 = fmaf(Rm[1][2], s2, fmaf(Rm[1][1], s1, Rm[1][0] * s0)) + t1;     \
    float x2 = fmaf(Rm[2][2], s2, fmaf(Rm[2][1], s1, Rm[2][0] * s0)) + t2;     \
    float xn = x0 * x0 + x1 * x1 + x2 * x2;                                    \
    xsv[tid] = make_float4(x0, x1, x2, xn);                                    \
    __syncthreads();                                                           \
    int rg = tid & 31, cq = tid >> 5;                                          \
    float4 xr0 = xsv[4 * rg + 0];                                              \
    float4 xr1 = xsv[4 * rg + 1];                                              \
    float4 xr2 = xsv[4 * rg + 2];                                              \
    float4 xr3 = xsv[4 * rg + 3];                                              \
    float racc0 = 3.402823466e38f, racc1 = 3.402823466e38f;                    \
    float racc2 = 3.402823466e38f, racc3 = 3.402823466e38f;                    \
    float cacc[32];                                                            \
    _Pragma("unroll")                                                          \
    for (int cj = 0; cj < 32; cj++) {                                          \
      float4 y = syv[(cq << 5) + cj];                                          \
      float cr0 = fmaf(xr0.z, y.z, fmaf(xr0.y, y.y, xr0.x * y.x));             \
      float d0 = (xr0.w + y.w) - 2.0f * cr0; d0 = fmaxf(d0, 0.0f);             \
      float cr1 = fmaf(xr1.z, y.z, fmaf(xr1.y, y.y, xr1.x * y.x));             \
      float d1 = (xr1.w + y.w) - 2.0f * cr1; d1 = fmaxf(d1, 0.0f);             \
      float cr2 = fmaf(xr2.z, y.z, fmaf(xr2.y, y.y, xr2.x * y.x));             \
      float d2_ = (xr2.w + y.w) - 2.0f * cr2; d2_ = fmaxf(d2_, 0.0f);          \
      float cr3 = fmaf(xr3.z, y.z, fmaf(xr3.y, y.y, xr3.x * y.x));             \
      float d3 = (xr3.w + y.w) - 2.0f * cr3; d3 = fmaxf(d3, 0.0f);             \
      racc0 = fminf(racc0, d0); racc1 = fminf(racc1, d1);                      \
      racc2 = fminf(racc2, d2_); racc3 = fminf(racc3, d3);                     \
      cacc[cj] = fminf(fminf(d0, d1), fminf(d2_, d3));                         \
    }                                                                          \
    rowpart[cq * 128 + 4 * rg + 0] = racc0;                                    \
    rowpart[cq * 128 + 4 * rg + 1] = racc1;                                    \
    rowpart[cq * 128 + 4 * rg + 2] = racc2;                                    \
    rowpart[cq * 128 + 4 * rg + 3] = racc3;                                    \
    float cv = 3.402823466e38f;                                                \
    _Pragma("unroll")                                                          \
    for (int ph = 0; ph < 4; ph++) {                                           \
      if ((rg >> 3) == ph) {                                                   \
        int r8 = rg & 7;                                                       \
        _Pragma("unroll")                                                      \
        for (int cj = 0; cj < 32; cj++)                                        \
          colp[r8 * 132 + (cq << 5) + cj] = cacc[cj];                          \
      }                                                                        \
      __syncthreads();                                                         \
      _Pragma("unroll")                                                        \
      for (int r8 = 0; r8 < 8; r8++)                                           \
        cv = fminf(cv, colp[r8 * 132 + tid]);                                  \
      __syncthreads();                                                         \
    }                                                                          \
    float rv = rowpart[tid];                                                   \
    rv = fminf(rv, rowpart[128 + tid]);                                        \
    rv = fminf(rv, rowpart[256 + tid]);                                        \
    rv = fminf(rv, rowpart[384 + tid]);                                        \
    __syncthreads();                                                           \
    rowpart[tid] = rv;                                                         \
    __syncthreads();                                                           \
    for (int s = 64; s > 0; s >>= 1) {                                         \
      if (tid < s) rowpart[tid] += rowpart[tid + s];                           \
      __syncthreads();                                                         \
    }                                                                          \
    float rowsum = rowpart[0];                                                 \
    __syncthreads();                                                           \
    rowpart[tid] = cv;                                                         \
    __syncthreads();                                                           \
    for (int s = 64; s > 0; s >>= 1) {                                         \
      if (tid < s) rowpart[tid] += rowpart[tid + s];                           \
      __syncthreads();                                                         \
    }                                                                          \
    if (tid == 0) OUTSTMT;                                                     \
  }

__global__ __launch_bounds__(128, 4) void eval_kernel(
    const float* __restrict__ srcb, const float* __restrict__ tgtb,
    const float* __restrict__ ynb, const float* __restrict__ pose,
    float* __restrict__ fout) {
  int blk = blockIdx.x;
  int b = blk / 50, p = blk % 50;
  int tid = threadIdx.x;
  __shared__ float4 syv[128];
  __shared__ float4 xsv[128];
  __shared__ float rowpart[512];
  __shared__ float colp[8 * 132];
  {
    float y0 = tgtb[(b * 128 + tid) * 3 + 0];
    float y1 = tgtb[(b * 128 + tid) * 3 + 1];
    float y2 = tgtb[(b * 128 + tid) * 3 + 2];
    syv[tid] = make_float4(y0, y1, y2, ynb[b * 128 + tid]);
  }
  float s0 = srcb[(b * 128 + tid) * 3 + 0];
  float s1 = srcb[(b * 128 + tid) * 3 + 1];
  float s2 = srcb[(b * 128 + tid) * 3 + 2];
  const float* v = pose + (b * 50 + p) * 6;
  EVAL_CORE_BODY(v[0], v[1], v[2], v[3], v[4], v[5],
                 fout[blk] = rowsum * 0.0078125f + rowpart[0] * 0.0078125f)
}

// ============================================================================
// fused DE step: selection on the fly + DE indices + trial, then eval trial.
// ============================================================================
__device__ __forceinline__ float eff_pop(const float* pop_prev,
                                         const float* fit_prev,
                                         const float* trial_prev,
                                         const float* tfit_prev,
                                         int bq, int d) {
  return (tfit_prev[bq] < fit_prev[bq]) ? trial_prev[bq * 6 + d]
                                        : pop_prev[bq * 6 + d];
}

__global__ __launch_bounds__(128, 4) void step_kernel(
    const float* __restrict__ srcb, const float* __restrict__ tgtb,
    const float* __restrict__ ynb,
    const float* __restrict__ pop_prev, const float* __restrict__ fit_prev,
    const float* __restrict__ trial_prev, const float* __restrict__ tfit_prev,
    float* __restrict__ pop_cur, float* __restrict__ fit_cur,
    float* __restrict__ trial_cur, float* __restrict__ tfit_cur, int it) {
  int blk = blockIdx.x;
  int b = blk / 50, p = blk % 50;
  int tid = threadIdx.x;
  __shared__ unsigned lbits[3 * 64];
  __shared__ int sel[3];
  __shared__ float strial[8];
  __shared__ float4 syv[128];
  __shared__ float4 xsv[128];
  __shared__ float rowpart[512];
  __shared__ float colp[8 * 132];

  U2 root = root_key();
  U2 kloop = split_key(root, 5, 4);
  U2 kit = split_key(kloop, 30, it);
  U2 ka = split_key(kit, 3, 0);
  U2 kb = split_key(kit, 3, 1);
  U2 kc = split_key(kit, 3, 2);

  for (int e = tid; e < 150; e += 128) {
    int r = e / 50, q = e % 50;
    U2 pk = split_key(ka, 96, r * 32 + b);
    U2 sub = split_key(pk, 2, 1);
    lbits[r * 64 + q] = random_bits(sub, 50, (unsigned)q);
  }
  {
    float y0 = tgtb[(b * 128 + tid) * 3 + 0];
    float y1 = tgtb[(b * 128 + tid) * 3 + 1];
    float y2 = tgtb[(b * 128 + tid) * 3 + 2];
    syv[tid] = make_float4(y0, y1, y2, ynb[b * 128 + tid]);
  }
  float s0 = srcb[(b * 128 + tid) * 3 + 0];
  float s1 = srcb[(b * 128 + tid) * 3 + 1];
  float s2 = srcb[(b * 128 + tid) * 3 + 2];
  __syncthreads();
  for (int e = tid; e < 150; e += 128) {
    int r = e / 50, q = e % 50;
    unsigned bq = lbits[r * 64 + q];
    int cnt = 0;
    for (int j = 0; j < 50; j++) {
      unsigned bj = lbits[r * 64 + j];
      cnt += (bj < bq || (bj == bq && j < q)) ? 1 : 0;
    }
    if (cnt == p) sel[r] = q;
  }
  __syncthreads();

  if (tid < 6) {
    int d = tid, bp = blk;
    int i1 = sel[0], i2 = sel[1], i3 = sel[2];
    float x1v = eff_pop(pop_prev, fit_prev, trial_prev, tfit_prev, b * 50 + i1, d);
    float x2v = eff_pop(pop_prev, fit_prev, trial_prev, tfit_prev, b * 50 + i2, d);
    float x3v = eff_pop(pop_prev, fit_prev, trial_prev, tfit_prev, b * 50 + i3, d);
    float mu = x1v + 0.8f * (x2v - x3v);
    if (d < 3) mu = fminf(fmaxf(mu, -ROTR), ROTR);
    else       mu = fminf(fmaxf(mu, -1.0f), 1.0f);
    U2 kc1 = split_key(kc, 2, 0), kc2 = split_key(kc, 2, 1);
    unsigned hb = random_bits(kc1, 1600, (unsigned)bp);
    unsigned lb = random_bits(kc2, 1600, (unsigned)bp);
    int jr = (int)((((hb % 6u) * 4u) + (lb % 6u)) % 6u);
    unsigned rb = random_bits(kb, 9600, (unsigned)(bp * 6 + d));
    float u = __uint_as_float((rb >> 9) | 0x3f800000u) - 1.0f;
    float pv = eff_pop(pop_prev, fit_prev, trial_prev, tfit_prev, bp, d);
    float tv = ((u < 0.9f) || (d == jr)) ? mu : pv;
    strial[d] = tv;
    trial_cur[bp * 6 + d] = tv;
    pop_cur[bp * 6 + d] = pv;
  } else if (tid == 6) {
    int bp = blk;
    float f = fit_prev[bp], tfv = tfit_prev[bp];
    fit_cur[bp] = (tfv < f) ? tfv : f;
  }
  __syncthreads();

  EVAL_CORE_BODY(strial[0], strial[1], strial[2], strial[3], strial[4],
                 strial[5],
                 tfit_cur[blk] = rowsum * 0.0078125f + rowpart[0] * 0.0078125f)
}

// ============================================================================
// final selection + argmin + R_best/t_best -> out[0:384)
// ============================================================================
__global__ __launch_bounds__(64) void final_kernel(
    float* __restrict__ pop, float* __restrict__ fit,
    const float* __restrict__ trial, const float* __restrict__ tfit,
    float* __restrict__ out) {
  int b = blockIdx.x, tid = threadIdx.x;
  __shared__ float fl[50];
  if (tid < 50) {
    int bp = b * 50 + tid;
    float f = fit[bp], tfv = tfit[bp];
    if (tfv < f) {
      f = tfv;
#pragma unroll
      for (int d = 0; d < 6; d++) pop[bp * 6 + d] = trial[bp * 6 + d];
    }
    fit[bp] = f;
    fl[tid] = f;
  }
  __syncthreads();
  if (tid == 0) {
    int best = 0;
    for (int q = 1; q < 50; q++)
      if (fl[q] < fl[best]) best = q;
    const float* v = pop + (b * 50 + best) * 6;
    float R[3][3];
    compute_R(v[0], v[1], v[2], R);
#pragma unroll
    for (int i = 0; i < 3; i++)
#pragma unroll
      for (int j = 0; j < 3; j++) out[b * 9 + i * 3 + j] = R[i][j];
    out[288 + b * 3 + 0] = v[3];
    out[288 + b * 3 + 1] = v[4];
    out[288 + b * 3 + 2] = v[5];
  }
}

// aligned = source @ R_best^T + t_best  -> out[384:)
__global__ __launch_bounds__(256) void aligned_kernel(
    const float* __restrict__ source, float* __restrict__ out) {
  int gid = blockIdx.x * 256 + threadIdx.x;  // 524288
  int b = gid >> 14;
  const float* R = out + b * 9;
  const float* t = out + 288 + b * 3;
  float s0 = source[(size_t)gid * 3 + 0];
  float s1 = source[(size_t)gid * 3 + 1];
  float s2 = source[(size_t)gid * 3 + 2];
  float a0 = fmaf(R[2], s2, fmaf(R[1], s1, R[0] * s0)) + t[0];
  float a1 = fmaf(R[5], s2, fmaf(R[4], s1, R[3] * s0)) + t[1];
  float a2 = fmaf(R[8], s2, fmaf(R[7], s1, R[6] * s0)) + t[2];
  out[384 + (size_t)gid * 3 + 0] = a0;
  out[384 + (size_t)gid * 3 + 1] = a1;
  out[384 + (size_t)gid * 3 + 2] = a2;
}

// ============================================================================
extern "C" void kernel_launch(void* const* d_in, const int* in_sizes, int n_in,
                              void* d_out, int out_size, void* d_ws,
                              size_t ws_size, hipStream_t stream) {
  const float* source = (const float*)d_in[0];
  const float* target = (const float*)d_in[1];
  float* out = (float*)d_out;
  char* ws = (char*)d_ws;

  // --- workspace layout, fully disjoint ---
  unsigned long long* sorted = (unsigned long long*)(ws + 0);   // 524288
  unsigned* rank_all = (unsigned*)(ws + 524288);                // 262144
  unsigned* x1buf    = (unsigned*)(ws + 786432);                // 131072
  int* idx           = (int*)(ws + 917504);                     // 1024
  unsigned* hist     = (unsigned*)(ws + 918528);                // 4096
  unsigned* basep    = (unsigned*)(ws + 922624);                // 4096
  unsigned* cursor   = (unsigned*)(ws + 926720);                // 4096
  float* srcb        = (float*)(ws + 930816);                   // 49152
  float* tgtb        = (float*)(ws + 979968);                   // 49152
  float* ynb         = (float*)(ws + 1029120);                  // 16384
  float* pop0        = (float*)(ws + 1045504);                  // 38400
  float* fit0        = (float*)(ws + 1083904);                  // 6400
  float* popA        = (float*)(ws + 1090304);                  // 38400
  float* fitA        = (float*)(ws + 1128704);                  // 6400
  float* trialA      = (float*)(ws + 1135104);                  // 38400
  float* tfitA       = (float*)(ws + 1173504);                  // 6400
  float* popB        = (float*)(ws + 1179904);                  // 38400
  float* fitB        = (float*)(ws + 1218304);                  // 6400
  float* trialB      = (float*)(ws + 1224704);                  // 38400
  float* tfitB       = (float*)(ws + 1263104);                  // 6400

  hipMemsetAsync(hist, 0, 4096, stream);
  hist_kernel<<<256, 256, 0, stream>>>(hist);
  prefix_kernel<<<1, 256, 0, stream>>>(hist, basep, cursor);
  scatterb_kernel<<<256, 256, 0, stream>>>(cursor, sorted);
  rank_kernel<<<256, 256, 0, stream>>>(sorted, basep, hist, rank_all);
  scatter_kernel<<<128, 256, 0, stream>>>(rank_all, x1buf);
  idx_kernel<<<128, 256, 0, stream>>>(rank_all, x1buf, idx);
  setup_kernel<<<32, 128, 0, stream>>>(source, target, idx, srcb, tgtb, ynb, pop0);
  eval_kernel<<<1600, 128, 0, stream>>>(srcb, tgtb, ynb, pop0, fit0);

  const float* pp = pop0; const float* pf = fit0;
  const float* pt = pop0; const float* ptf = fit0;  // it=0: selection no-op
  for (int it = 0; it < 30; it++) {
    float* cp  = (it & 1) ? popB : popA;
    float* cf  = (it & 1) ? fitB : fitA;
    float* ct  = (it & 1) ? trialB : trialA;
    float* ctf = (it & 1) ? tfitB : tfitA;
    step_kernel<<<1600, 128, 0, stream>>>(srcb, tgtb, ynb, pp, pf, pt, ptf,
                                          cp, cf, ct, ctf, it);
    pp = cp; pf = cf; pt = ct; ptf = ctf;
  }
  final_kernel<<<32, 64, 0, stream>>>(popB, fitB, trialB, tfitB, out);
  aligned_kernel<<<2048, 256, 0, stream>>>(source, out);
}

// Round 6
// 495.039 us; speedup vs baseline: 3.1874x; 1.3918x over previous
//
#include <hip/hip_runtime.h>
#include <stdint.h>

// ============================================================================
// JAX threefry2x32 PRNG reproduction (partitionable semantics, verified R0).
// ============================================================================
struct U2 { unsigned a, b; };

__device__ __forceinline__ unsigned rotl32(unsigned v, int r) {
  return (v << r) | (v >> (32 - r));
}

__device__ __forceinline__ U2 tf(U2 k, unsigned x0, unsigned x1) {
  unsigned ks0 = k.a, ks1 = k.b, ks2 = k.a ^ k.b ^ 0x1BD11BDAu;
  x0 += ks0; x1 += ks1;
#define TFG(RA, RB, RC, RD, KA, KB, INC)                  \
  x0 += x1; x1 = rotl32(x1, RA); x1 ^= x0;                \
  x0 += x1; x1 = rotl32(x1, RB); x1 ^= x0;                \
  x0 += x1; x1 = rotl32(x1, RC); x1 ^= x0;                \
  x0 += x1; x1 = rotl32(x1, RD); x1 ^= x0;                \
  x0 += KA; x1 += KB + INC;
  TFG(13, 15, 26, 6, ks1, ks2, 1u)
  TFG(17, 29, 16, 24, ks2, ks0, 2u)
  TFG(13, 15, 26, 6, ks0, ks1, 3u)
  TFG(17, 29, 16, 24, ks1, ks2, 4u)
  TFG(13, 15, 26, 6, ks2, ks0, 5u)
#undef TFG
  U2 r; r.a = x0; r.b = x1; return r;
}

__device__ __forceinline__ U2 split_key(U2 key, int num, int j) {
  (void)num;
  return tf(key, 0u, (unsigned)j);
}
__device__ __forceinline__ unsigned random_bits(U2 key, int n, unsigned e) {
  (void)n;
  U2 r = tf(key, 0u, e);
  return r.a ^ r.b;
}

__device__ __forceinline__ U2 root_key() { U2 k; k.a = 0u; k.b = 42u; return k; }

__device__ __forceinline__ float jax_uniform(U2 key, int n, unsigned e,
                                             float minv, float maxv) {
  unsigned b = random_bits(key, n, e);
  float u = __uint_as_float((b >> 9) | 0x3f800000u) - 1.0f;
  float r = u * (maxv - minv) + minv;
  return fmaxf(minv, r);
}

#define ROTR 0.7853981633974483f

__device__ __forceinline__ void compute_R(float vx, float vy, float vz,
                                          float R[3][3]) {
  float nsq = vx * vx + vy * vy + vz * vz;
  float theta = sqrtf(nsq);
  if (theta < 1e-8f) {
    R[0][0] = 1.f; R[0][1] = 0.f; R[0][2] = 0.f;
    R[1][0] = 0.f; R[1][1] = 1.f; R[1][2] = 0.f;
    R[2][0] = 0.f; R[2][1] = 0.f; R[2][2] = 1.f;
    return;
  }
  float m = fmaxf(theta, 1e-8f);
  float kx = vx / m, ky = vy / m, kz = vz / m;
  float s = sinf(theta), c = cosf(theta);
  float K[3][3] = {{0.f, -kz, ky}, {kz, 0.f, -kx}, {-ky, kx, 0.f}};
  float K2[3][3];
#pragma unroll
  for (int i = 0; i < 3; i++)
#pragma unroll
    for (int j = 0; j < 3; j++)
      K2[i][j] = fmaf(K[i][2], K[2][j], fmaf(K[i][1], K[1][j], K[i][0] * K[0][j]));
  float omc = 1.0f - c;
#pragma unroll
  for (int i = 0; i < 3; i++)
#pragma unroll
    for (int j = 0; j < 3; j++)
      R[i][j] = ((i == j) ? 1.0f : 0.0f) + s * K[i][j] + omc * K2[i][j];
}

// composite sort key for stream s (0:src r1, 1:src r2, 2:tgt r1, 3:tgt r2)
__device__ __forceinline__ unsigned long long make_composite(int s, int i) {
  U2 root = root_key();
  U2 kp = split_key(root, 5, s >> 1);
  U2 key;
  if ((s & 1) == 0) {
    key = split_key(kp, 2, 1);
  } else {
    U2 kA = split_key(kp, 2, 0);
    key = split_key(kA, 2, 1);
  }
  unsigned rb = random_bits(key, 16384, (unsigned)i);
  return ((unsigned long long)rb << 32) | (unsigned)i;
}

// ============================================================================
// Bucket-sort rank pipeline (verified R3).
// ============================================================================
__global__ __launch_bounds__(256) void hist_kernel(unsigned* __restrict__ hist) {
  int gid = blockIdx.x * 256 + threadIdx.x;  // 65536
  int s = gid >> 14, i = gid & 16383;
  unsigned long long c = make_composite(s, i);
  unsigned bucket = (unsigned)(c >> 56);
  atomicAdd(&hist[s * 256 + bucket], 1u);
}

__global__ __launch_bounds__(256) void prefix_kernel(
    const unsigned* __restrict__ hist, unsigned* __restrict__ base,
    unsigned* __restrict__ cursor) {
  __shared__ unsigned h[4][256];
  int t = threadIdx.x;
#pragma unroll
  for (int s = 0; s < 4; s++) h[s][t] = hist[s * 256 + t];
  __syncthreads();
#pragma unroll
  for (int s = 0; s < 4; s++) {
    unsigned acc = 0;
    for (int j = 0; j < 256; j++) acc += (j < t) ? h[s][j] : 0u;
    base[s * 256 + t] = acc;
    cursor[s * 256 + t] = acc;
  }
}

__global__ __launch_bounds__(256) void scatterb_kernel(
    unsigned* __restrict__ cursor, unsigned long long* __restrict__ sorted) {
  int gid = blockIdx.x * 256 + threadIdx.x;  // 65536
  int s = gid >> 14, i = gid & 16383;
  unsigned long long c = make_composite(s, i);
  unsigned bucket = (unsigned)(c >> 56);
  unsigned pos = atomicAdd(&cursor[s * 256 + bucket], 1u);
  sorted[(s << 14) + pos] = c;
}

__global__ __launch_bounds__(256) void rank_kernel(
    const unsigned long long* __restrict__ sorted,
    const unsigned* __restrict__ base, const unsigned* __restrict__ hist,
    unsigned* __restrict__ rank_all) {
  int gid = blockIdx.x * 256 + threadIdx.x;  // 65536
  int s = gid >> 14, k = gid & 16383;
  unsigned long long c = sorted[(s << 14) + k];
  unsigned bucket = (unsigned)(c >> 56);
  unsigned b0 = base[s * 256 + bucket];
  unsigned cnt = hist[s * 256 + bucket];
  unsigned less = 0;
  for (unsigned j = 0; j < cnt; j++)
    less += (sorted[(s << 14) + b0 + j] < c) ? 1u : 0u;
  unsigned i = (unsigned)(c & 0xffffffffull);
  rank_all[(s << 14) + i] = b0 + less;
}

// x1[perm][rank1[i]] = i   (streams 0,2)
__global__ __launch_bounds__(256) void scatter_kernel(
    const unsigned* __restrict__ rank_all, unsigned* __restrict__ x1buf) {
  int gid = blockIdx.x * 256 + threadIdx.x;  // 32768
  int perm = gid >> 14, i = gid & 16383;
  unsigned r = rank_all[((perm * 2) << 14) + i];
  x1buf[(perm << 14) + (int)r] = (unsigned)i;
}

// idx[perm][rank2[i]] = x1[perm][i] for rank2[i] < 128  (streams 1,3)
__global__ __launch_bounds__(256) void idx_kernel(
    const unsigned* __restrict__ rank_all, const unsigned* __restrict__ x1buf,
    int* __restrict__ idx) {
  int gid = blockIdx.x * 256 + threadIdx.x;  // 32768
  int perm = gid >> 14, i = gid & 16383;
  unsigned r = rank_all[((perm * 2 + 1) << 14) + i];
  if (r < 128u) idx[perm * 128 + (int)r] = (int)x1buf[(perm << 14) + i];
}

// ============================================================================
// setup: gather subsets, precompute yn, init population.
// ============================================================================
__global__ __launch_bounds__(128) void setup_kernel(
    const float* __restrict__ source, const float* __restrict__ target,
    const int* __restrict__ idx, float* __restrict__ src,
    float* __restrict__ tgt, float* __restrict__ yn, float* __restrict__ pop) {
  int b = blockIdx.x, tid = threadIdx.x;
  int is = idx[tid], it = idx[128 + tid];
#pragma unroll
  for (int d = 0; d < 3; d++)
    src[(b * 128 + tid) * 3 + d] = source[((size_t)b * 16384 + is) * 3 + d];
  float y0 = target[((size_t)b * 16384 + it) * 3 + 0];
  float y1 = target[((size_t)b * 16384 + it) * 3 + 1];
  float y2 = target[((size_t)b * 16384 + it) * 3 + 2];
  tgt[(b * 128 + tid) * 3 + 0] = y0;
  tgt[(b * 128 + tid) * 3 + 1] = y1;
  tgt[(b * 128 + tid) * 3 + 2] = y2;
  yn[b * 128 + tid] = y0 * y0 + y1 * y1 + y2 * y2;

  U2 root = root_key();
  U2 k2 = split_key(root, 5, 2);
  U2 k3 = split_key(root, 5, 3);
  for (int e = tid; e < 300; e += 128) {
    int p = e / 6, d = e % 6;
    float val;
    if (p == 0) {
      val = 0.0f;
    } else {
      unsigned ridx = (unsigned)((b * 50 + p) * 3 + (d % 3));
      if (d < 3) val = jax_uniform(k2, 4800, ridx, -ROTR, ROTR);
      else       val = jax_uniform(k3, 4800, ridx, -1.0f, 1.0f);
    }
    pop[(b * 50 + p) * 6 + d] = val;
  }
}

// ============================================================================
// perm precompute: one block per (it, b); stores perm[rank] = q for the 3 DE
// shuffles. perms[((it*32+b)*3 + r)*50 + rank] = q.  (math identical to the
// in-step derivation used in R3/R5)
// ============================================================================
__global__ __launch_bounds__(64) void perm_kernel(int* __restrict__ permsg) {
  int blk = blockIdx.x;  // 960 = 30 its * 32 batches
  int it = blk >> 5, b = blk & 31;
  int tid = threadIdx.x;
  __shared__ unsigned pbits[3][64];
  U2 root = root_key();
  U2 kloop = split_key(root, 5, 4);
  U2 kit = split_key(kloop, 30, it);
  U2 ka = split_key(kit, 3, 0);
  for (int e = tid; e < 150; e += 64) {
    int r = e / 50, q = e % 50;
    U2 pk = split_key(ka, 96, r * 32 + b);
    U2 sub = split_key(pk, 2, 1);
    pbits[r][q] = random_bits(sub, 50, (unsigned)q);
  }
  __syncthreads();
  for (int e = tid; e < 150; e += 64) {
    int r = e / 50, q = e % 50;
    unsigned bq = pbits[r][q];
    int cnt = 0;
    for (int j = 0; j < 50; j++) {
      unsigned bj = pbits[r][j];
      cnt += (bj < bq || (bj == bq && j < q)) ? 1 : 0;
    }
    permsg[(blk * 3 + r) * 50 + cnt] = q;
  }
}

// ============================================================================
// Chamfer eval core, shuffle-reduction variant.
// d2 values, min sets, and sum-tree pairing are bitwise identical to R5:
//  - col-min across the 32 row-threads via in-register lane butterfly
//    (fminf is exact => order-independent)
//  - 128-sum trees: s=64 folded through LDS, s=32..1 via shfl_xor (provably
//    the same pairing as red[t]+=red[t+s])
// Return value valid on tid==0. 3 __syncthreads per call.
// ============================================================================
__device__ __forceinline__ float eval_pose_core(
    float p0, float p1, float p2, float p3, float p4, float p5,
    float s0, float s1, float s2, int tid, const float4* syv, float4* xsv,
    float* rowpart, float* red1, float* red2) {
  float Rm[3][3];
  compute_R(p0, p1, p2, Rm);
  float x0 = fmaf(Rm[0][2], s2, fmaf(Rm[0][1], s1, Rm[0][0] * s0)) + p3;
  float x1 = fmaf(Rm[1][2], s2, fmaf(Rm[1][1], s1, Rm[1][0] * s0)) + p4;
  float x2 = fmaf(Rm[2][2], s2, fmaf(Rm[2][1], s1, Rm[2][0] * s0)) + p5;
  float xn = x0 * x0 + x1 * x1 + x2 * x2;
  xsv[tid] = make_float4(x0, x1, x2, xn);
  __syncthreads();
  int rg = tid & 31, cq = tid >> 5;
  float4 xr0 = xsv[4 * rg + 0];
  float4 xr1 = xsv[4 * rg + 1];
  float4 xr2 = xsv[4 * rg + 2];
  float4 xr3 = xsv[4 * rg + 3];
  float racc0 = 3.402823466e38f, racc1 = 3.402823466e38f;
  float racc2 = 3.402823466e38f, racc3 = 3.402823466e38f;
  float cacc[32];
#pragma unroll
  for (int cj = 0; cj < 32; cj++) {
    float4 y = syv[(cq << 5) + cj];
    float cr0 = fmaf(xr0.z, y.z, fmaf(xr0.y, y.y, xr0.x * y.x));
    float d0 = (xr0.w + y.w) - 2.0f * cr0; d0 = fmaxf(d0, 0.0f);
    float cr1 = fmaf(xr1.z, y.z, fmaf(xr1.y, y.y, xr1.x * y.x));
    float d1 = (xr1.w + y.w) - 2.0f * cr1; d1 = fmaxf(d1, 0.0f);
    float cr2 = fmaf(xr2.z, y.z, fmaf(xr2.y, y.y, xr2.x * y.x));
    float d2_ = (xr2.w + y.w) - 2.0f * cr2; d2_ = fmaxf(d2_, 0.0f);
    float cr3 = fmaf(xr3.z, y.z, fmaf(xr3.y, y.y, xr3.x * y.x));
    float d3 = (xr3.w + y.w) - 2.0f * cr3; d3 = fmaxf(d3, 0.0f);
    racc0 = fminf(racc0, d0); racc1 = fminf(racc1, d1);
    racc2 = fminf(racc2, d2_); racc3 = fminf(racc3, d3);
    cacc[cj] = fminf(fminf(d0, d1), fminf(d2_, d3));
  }
  rowpart[cq * 128 + 4 * rg + 0] = racc0;
  rowpart[cq * 128 + 4 * rg + 1] = racc1;
  rowpart[cq * 128 + 4 * rg + 2] = racc2;
  rowpart[cq * 128 + 4 * rg + 3] = racc3;
  // ---- in-register column-min butterfly across the 32 lanes of this half ----
#pragma unroll
  for (int m = 16; m >= 1; m >>= 1) {
    bool hi = (rg & m) != 0;
#pragma unroll
    for (int j = 0; j < m; j++) {
      float lo_v = cacc[j], hi_v = cacc[j + m];
      float mine = hi ? hi_v : lo_v;
      float send = hi ? lo_v : hi_v;
      float recv = __shfl_xor(send, m, 64);
      cacc[j] = fminf(mine, recv);
    }
  }
  float colmin = cacc[0];  // column tid
  __syncthreads();
  float rv = rowpart[tid];
  rv = fminf(rv, rowpart[128 + tid]);
  rv = fminf(rv, rowpart[256 + tid]);
  rv = fminf(rv, rowpart[384 + tid]);
  red1[tid] = rv;
  red2[tid] = colmin;
  __syncthreads();
  int l = tid & 63;
  float v1 = red1[l] + red1[l + 64];
  float v2 = red2[l] + red2[l + 64];
#pragma unroll
  for (int m = 32; m >= 1; m >>= 1) {
    v1 += __shfl_xor(v1, m, 64);
    v2 += __shfl_xor(v2, m, 64);
  }
  return v1 * 0.0078125f + v2 * 0.0078125f;
}

__global__ __launch_bounds__(128, 4) void eval_kernel(
    const float* __restrict__ srcb, const float* __restrict__ tgtb,
    const float* __restrict__ ynb, const float* __restrict__ pose,
    float* __restrict__ fout) {
  int blk = blockIdx.x;
  int b = blk / 50, p = blk % 50;
  int tid = threadIdx.x;
  __shared__ float4 syv[128];
  __shared__ float4 xsv[128];
  __shared__ float rowpart[512];
  __shared__ float red1[128];
  __shared__ float red2[128];
  {
    float y0 = tgtb[(b * 128 + tid) * 3 + 0];
    float y1 = tgtb[(b * 128 + tid) * 3 + 1];
    float y2 = tgtb[(b * 128 + tid) * 3 + 2];
    syv[tid] = make_float4(y0, y1, y2, ynb[b * 128 + tid]);
  }
  float s0 = srcb[(b * 128 + tid) * 3 + 0];
  float s1 = srcb[(b * 128 + tid) * 3 + 1];
  float s2 = srcb[(b * 128 + tid) * 3 + 2];
  const float* v = pose + (b * 50 + p) * 6;
  float f = eval_pose_core(v[0], v[1], v[2], v[3], v[4], v[5],
                           s0, s1, s2, tid, syv, xsv, rowpart, red1, red2);
  if (tid == 0) fout[blk] = f;
}

// ============================================================================
// fused DE step: selection on the fly + precomputed perm lookup + trial,
// then eval trial.
// ============================================================================
__device__ __forceinline__ float eff_pop(const float* pop_prev,
                                         const float* fit_prev,
                                         const float* trial_prev,
                                         const float* tfit_prev,
                                         int bq, int d) {
  return (tfit_prev[bq] < fit_prev[bq]) ? trial_prev[bq * 6 + d]
                                        : pop_prev[bq * 6 + d];
}

__global__ __launch_bounds__(128, 4) void step_kernel(
    const float* __restrict__ srcb, const float* __restrict__ tgtb,
    const float* __restrict__ ynb, const int* __restrict__ permsg,
    const float* __restrict__ pop_prev, const float* __restrict__ fit_prev,
    const float* __restrict__ trial_prev, const float* __restrict__ tfit_prev,
    float* __restrict__ pop_cur, float* __restrict__ fit_cur,
    float* __restrict__ trial_cur, float* __restrict__ tfit_cur, int it) {
  int blk = blockIdx.x;
  int b = blk / 50, p = blk % 50;
  int tid = threadIdx.x;
  __shared__ float strial[8];
  __shared__ float4 syv[128];
  __shared__ float4 xsv[128];
  __shared__ float rowpart[512];
  __shared__ float red1[128];
  __shared__ float red2[128];

  {
    float y0 = tgtb[(b * 128 + tid) * 3 + 0];
    float y1 = tgtb[(b * 128 + tid) * 3 + 1];
    float y2 = tgtb[(b * 128 + tid) * 3 + 2];
    syv[tid] = make_float4(y0, y1, y2, ynb[b * 128 + tid]);
  }
  float s0 = srcb[(b * 128 + tid) * 3 + 0];
  float s1 = srcb[(b * 128 + tid) * 3 + 1];
  float s2 = srcb[(b * 128 + tid) * 3 + 2];

  if (tid < 6) {
    int d = tid, bp = blk;
    int base = ((it * 32 + b) * 3) * 50;
    int i1 = permsg[base + p];
    int i2 = permsg[base + 50 + p];
    int i3 = permsg[base + 100 + p];
    float x1v = eff_pop(pop_prev, fit_prev, trial_prev, tfit_prev, b * 50 + i1, d);
    float x2v = eff_pop(pop_prev, fit_prev, trial_prev, tfit_prev, b * 50 + i2, d);
    float x3v = eff_pop(pop_prev, fit_prev, trial_prev, tfit_prev, b * 50 + i3, d);
    float mu = x1v + 0.8f * (x2v - x3v);
    if (d < 3) mu = fminf(fmaxf(mu, -ROTR), ROTR);
    else       mu = fminf(fmaxf(mu, -1.0f), 1.0f);
    U2 root = root_key();
    U2 kloop = split_key(root, 5, 4);
    U2 kit = split_key(kloop, 30, it);
    U2 kb = split_key(kit, 3, 1);
    U2 kc = split_key(kit, 3, 2);
    U2 kc1 = split_key(kc, 2, 0), kc2 = split_key(kc, 2, 1);
    unsigned hb = random_bits(kc1, 1600, (unsigned)bp);
    unsigned lb = random_bits(kc2, 1600, (unsigned)bp);
    int jr = (int)((((hb % 6u) * 4u) + (lb % 6u)) % 6u);
    unsigned rb = random_bits(kb, 9600, (unsigned)(bp * 6 + d));
    float u = __uint_as_float((rb >> 9) | 0x3f800000u) - 1.0f;
    float pv = eff_pop(pop_prev, fit_prev, trial_prev, tfit_prev, bp, d);
    float tv = ((u < 0.9f) || (d == jr)) ? mu : pv;
    strial[d] = tv;
    trial_cur[bp * 6 + d] = tv;
    pop_cur[bp * 6 + d] = pv;
  } else if (tid == 6) {
    int bp = blk;
    float f = fit_prev[bp], tfv = tfit_prev[bp];
    fit_cur[bp] = (tfv < f) ? tfv : f;
  }
  __syncthreads();

  float f = eval_pose_core(strial[0], strial[1], strial[2], strial[3],
                           strial[4], strial[5],
                           s0, s1, s2, tid, syv, xsv, rowpart, red1, red2);
  if (tid == 0) tfit_cur[blk] = f;
}

// ============================================================================
// aligned + final selection fused: each block redundantly computes its batch's
// best particle (same first-min argmin as reference), transforms its 256
// points; one block per batch also writes R_best/t_best to out[0:384).
// ============================================================================
__global__ __launch_bounds__(256) void aligned_kernel(
    const float* __restrict__ source, const float* __restrict__ fit,
    const float* __restrict__ tfit, const float* __restrict__ pop,
    const float* __restrict__ trial, float* __restrict__ out) {
  int blk = blockIdx.x;  // 2048; 64 blocks per batch
  int b = blk >> 6;
  int tid = threadIdx.x;
  __shared__ float fl[64];
  __shared__ float Rsh[12];
  if (tid < 50) {
    int bp = b * 50 + tid;
    float f = fit[bp], tfv = tfit[bp];
    fl[tid] = (tfv < f) ? tfv : f;
  }
  __syncthreads();
  if (tid == 0) {
    int best = 0;
    for (int q = 1; q < 50; q++)
      if (fl[q] < fl[best]) best = q;
    int bp = b * 50 + best;
    bool useT = tfit[bp] < fit[bp];
    const float* v = useT ? (trial + bp * 6) : (pop + bp * 6);
    float R[3][3];
    compute_R(v[0], v[1], v[2], R);
#pragma unroll
    for (int i = 0; i < 3; i++)
#pragma unroll
      for (int j = 0; j < 3; j++) Rsh[i * 3 + j] = R[i][j];
    Rsh[9] = v[3]; Rsh[10] = v[4]; Rsh[11] = v[5];
    if ((blk & 63) == 0) {
#pragma unroll
      for (int e = 0; e < 9; e++) out[b * 9 + e] = Rsh[e];
      out[288 + b * 3 + 0] = v[3];
      out[288 + b * 3 + 1] = v[4];
      out[288 + b * 3 + 2] = v[5];
    }
  }
  __syncthreads();
  int gid = blk * 256 + tid;  // 524288
  float s0 = source[(size_t)gid * 3 + 0];
  float s1 = source[(size_t)gid * 3 + 1];
  float s2 = source[(size_t)gid * 3 + 2];
  float a0 = fmaf(Rsh[2], s2, fmaf(Rsh[1], s1, Rsh[0] * s0)) + Rsh[9];
  float a1 = fmaf(Rsh[5], s2, fmaf(Rsh[4], s1, Rsh[3] * s0)) + Rsh[10];
  float a2 = fmaf(Rsh[8], s2, fmaf(Rsh[7], s1, Rsh[6] * s0)) + Rsh[11];
  out[384 + (size_t)gid * 3 + 0] = a0;
  out[384 + (size_t)gid * 3 + 1] = a1;
  out[384 + (size_t)gid * 3 + 2] = a2;
}

// ============================================================================
extern "C" void kernel_launch(void* const* d_in, const int* in_sizes, int n_in,
                              void* d_out, int out_size, void* d_ws,
                              size_t ws_size, hipStream_t stream) {
  const float* source = (const float*)d_in[0];
  const float* target = (const float*)d_in[1];
  float* out = (float*)d_out;
  char* ws = (char*)d_ws;

  // --- workspace layout ---
  // [0, 786432): sorted (512K) + rank_all head -- both dead after idx_kernel;
  //              then reused for perms (576000 B).
  unsigned long long* sorted = (unsigned long long*)(ws + 0);   // 524288
  int* permsg        = (int*)(ws + 0);                          // 576000 (late)
  unsigned* rank_all = (unsigned*)(ws + 524288);                // 262144
  unsigned* x1buf    = (unsigned*)(ws + 786432);                // 131072
  int* idx           = (int*)(ws + 917504);                     // 1024
  unsigned* hist     = (unsigned*)(ws + 918528);                // 4096
  unsigned* basep    = (unsigned*)(ws + 922624);                // 4096
  unsigned* cursor   = (unsigned*)(ws + 926720);                // 4096
  float* srcb        = (float*)(ws + 930816);                   // 49152
  float* tgtb        = (float*)(ws + 979968);                   // 49152
  float* ynb         = (float*)(ws + 1029120);                  // 16384
  float* pop0        = (float*)(ws + 1045504);                  // 38400
  float* fit0        = (float*)(ws + 1083904);                  // 6400
  float* popA        = (float*)(ws + 1090304);                  // 38400
  float* fitA        = (float*)(ws + 1128704);                  // 6400
  float* trialA      = (float*)(ws + 1135104);                  // 38400
  float* tfitA       = (float*)(ws + 1173504);                  // 6400
  float* popB        = (float*)(ws + 1179904);                  // 38400
  float* fitB        = (float*)(ws + 1218304);                  // 6400
  float* trialB      = (float*)(ws + 1224704);                  // 38400
  float* tfitB       = (float*)(ws + 1263104);                  // 6400

  hipMemsetAsync(hist, 0, 4096, stream);
  hist_kernel<<<256, 256, 0, stream>>>(hist);
  prefix_kernel<<<1, 256, 0, stream>>>(hist, basep, cursor);
  scatterb_kernel<<<256, 256, 0, stream>>>(cursor, sorted);
  rank_kernel<<<256, 256, 0, stream>>>(sorted, basep, hist, rank_all);
  scatter_kernel<<<128, 256, 0, stream>>>(rank_all, x1buf);
  idx_kernel<<<128, 256, 0, stream>>>(rank_all, x1buf, idx);
  setup_kernel<<<32, 128, 0, stream>>>(source, target, idx, srcb, tgtb, ynb, pop0);
  perm_kernel<<<960, 64, 0, stream>>>(permsg);  // overwrites sorted/rank_all
  eval_kernel<<<1600, 128, 0, stream>>>(srcb, tgtb, ynb, pop0, fit0);

  const float* pp = pop0; const float* pf = fit0;
  const float* pt = pop0; const float* ptf = fit0;  // it=0: selection no-op
  for (int it = 0; it < 30; it++) {
    float* cp  = (it & 1) ? popB : popA;
    float* cf  = (it & 1) ? fitB : fitA;
    float* ct  = (it & 1) ? trialB : trialA;
    float* ctf = (it & 1) ? tfitB : tfitA;
    step_kernel<<<1600, 128, 0, stream>>>(srcb, tgtb, ynb, permsg,
                                          pp, pf, pt, ptf,
                                          cp, cf, ct, ctf, it);
    pp = cp; pf = cf; pt = ct; ptf = ctf;
  }
  // it=29 (odd) wrote the B buffers
  aligned_kernel<<<2048, 256, 0, stream>>>(source, fitB, tfitB, popB, trialB,
                                           out);
}